// Round 1
// baseline (1069.825 us; speedup 1.0000x reference)
//
#include <hip/hip_runtime.h>

#define HEADS 4
#define DHEAD 128
#define DIM   512
#define NTOK  1024     // 32*32
#define BATCH 16
#define OCH   1536     // 3 * HEADS * DHEAD

// ---------------------------------------------------------------------------
// Kernel 1: QKV projection (per-batch GEMM  O[o,i] = sum_c W[o,c] * F[b,c,i])
// fused with rearrange to q/k/v [b][h][i][d], q *= scale, k += emb(i).
// Tile: 64(o) x 64(i), K-step 16, 256 threads, 4x4 per-thread micro-tile.
// ---------------------------------------------------------------------------
#define K1_BO 64
#define K1_BI 64
#define K1_KT 16

__global__ __launch_bounds__(256)
void qkv_kernel(const float* __restrict__ F, const float* __restrict__ W,
                const float* __restrict__ EH, const float* __restrict__ EW,
                float* __restrict__ q, float* __restrict__ k, float* __restrict__ v)
{
    __shared__ float As[K1_KT][K1_BO + 4];   // As[kk][o]  (W transposed in-tile)
    __shared__ float Bs[K1_KT][K1_BI + 4];   // Bs[kk][i]

    const int b  = blockIdx.z;
    const int oo = blockIdx.x * K1_BO;
    const int ii = blockIdx.y * K1_BI;

    const int tid = threadIdx.x;
    const int tx = tid & 15;     // -> o micro-tile
    const int ty = tid >> 4;     // -> i micro-tile

    float acc[4][4];             // [r: i][c: o]
#pragma unroll
    for (int r = 0; r < 4; ++r)
#pragma unroll
        for (int c = 0; c < 4; ++c) acc[r][c] = 0.f;

    const int arow = tid >> 2;          // 0..63 (o within tile)
    const int ac0  = (tid & 3) * 4;     // 0,4,8,12 (k within tile)
    const int brow = tid >> 4;          // 0..15 (k within tile)
    const int bf0  = (tid & 15) * 4;    // 0..60 (i within tile)

    for (int kt = 0; kt < DIM; kt += K1_KT) {
        const float4 w4 = *(const float4*)(&W[(size_t)(oo + arow) * DIM + kt + ac0]);
        const float4 f4 = *(const float4*)(&F[((size_t)b * DIM + kt + brow) * NTOK + ii + bf0]);
        As[ac0 + 0][arow] = w4.x;
        As[ac0 + 1][arow] = w4.y;
        As[ac0 + 2][arow] = w4.z;
        As[ac0 + 3][arow] = w4.w;
        *(float4*)(&Bs[brow][bf0]) = f4;
        __syncthreads();
#pragma unroll
        for (int kk = 0; kk < K1_KT; ++kk) {
            const float4 a4 = *(const float4*)(&As[kk][tx * 4]);
            const float4 b4 = *(const float4*)(&Bs[kk][ty * 4]);
            acc[0][0] += b4.x * a4.x; acc[0][1] += b4.x * a4.y; acc[0][2] += b4.x * a4.z; acc[0][3] += b4.x * a4.w;
            acc[1][0] += b4.y * a4.x; acc[1][1] += b4.y * a4.y; acc[1][2] += b4.y * a4.z; acc[1][3] += b4.y * a4.w;
            acc[2][0] += b4.z * a4.x; acc[2][1] += b4.z * a4.y; acc[2][2] += b4.z * a4.z; acc[2][3] += b4.z * a4.w;
            acc[3][0] += b4.w * a4.x; acc[3][1] += b4.w * a4.y; acc[3][2] += b4.w * a4.z; acc[3][3] += b4.w * a4.w;
        }
        __syncthreads();
    }

    // epilogue: o = s*512 + h*128 + d  ->  dst[b][h][i][d]
    const int ob = oo + tx * 4;          // 4 consecutive o (never cross s/h/128 blocks)
    const int s  = ob >> 9;
    const int h  = (ob >> 7) & 3;
    const int d0 = ob & 127;
    const float scale = 0.08838834764831845f;   // 128^-0.5

    float* dst = (s == 0) ? q : (s == 1) ? k : v;
    const size_t rowbase = ((size_t)b * HEADS + h) * NTOK;

#pragma unroll
    for (int r = 0; r < 4; ++r) {
        const int i = ii + ty * 4 + r;
        float4 o4;
        o4.x = acc[r][0]; o4.y = acc[r][1]; o4.z = acc[r][2]; o4.w = acc[r][3];
        if (s == 0) {
            o4.x *= scale; o4.y *= scale; o4.z *= scale; o4.w *= scale;
        } else if (s == 1) {
            // fold absolute-position bias into k:  k'[i] = k[i] + emb_h[i>>5] + emb_w[i&31]
            const float4 eh = *(const float4*)(&EH[(i >> 5) * DHEAD + d0]);
            const float4 ew = *(const float4*)(&EW[(i & 31) * DHEAD + d0]);
            o4.x += eh.x + ew.x; o4.y += eh.y + ew.y; o4.z += eh.z + ew.z; o4.w += eh.w + ew.w;
        }
        *(float4*)(&dst[(rowbase + i) * DHEAD + d0]) = o4;
    }
}

// ---------------------------------------------------------------------------
// Kernel 2: flash attention, fp32 vector.
// Block = (b,h, 64-row q tile), 256 threads, j-tiles of 64.
// Qs/Ks stored transposed [d][i] for float4 rank-1 updates.
// ---------------------------------------------------------------------------
#define BI 64
#define BJ 64

__global__ __launch_bounds__(256)
void attn_kernel(const float* __restrict__ q, const float* __restrict__ k,
                 const float* __restrict__ v, float* __restrict__ out)
{
    __shared__ float Qs[DHEAD][BI + 4];      // [d][i]
    __shared__ float Ks[DHEAD][BJ + 4];      // [d][j]  (reused as Od[d][i] in epilogue)
    __shared__ float Vs[BJ][DHEAD + 4];      // [j][d]
    __shared__ float Ps[BJ][BI + 4];         // [j][i]

    const int ii = blockIdx.x * BI;
    const int bh = blockIdx.y;
    const size_t base = (size_t)bh * NTOK * DHEAD;

    const int tid = threadIdx.x;
    const int tx = tid & 15;
    const int ty = tid >> 4;

    // stage Q transposed (once)
    {
        const int i = tid & 63;
        const int c = tid >> 6;      // 4 chunks of 32 d
        const float* src = &q[base + (size_t)(ii + i) * DHEAD + c * 32];
#pragma unroll
        for (int u = 0; u < 8; ++u) {
            const float4 t4 = *(const float4*)(src + u * 4);
            const int d = c * 32 + u * 4;
            Qs[d + 0][i] = t4.x; Qs[d + 1][i] = t4.y; Qs[d + 2][i] = t4.z; Qs[d + 3][i] = t4.w;
        }
    }

    float m[4], l[4];
#pragma unroll
    for (int r = 0; r < 4; ++r) { m[r] = -3.0e38f; l[r] = 0.f; }
    float o[4][8];   // rows i=ty*4+r ; cols d = tx*4+c (c<4) and 64+tx*4+(c-4)
#pragma unroll
    for (int r = 0; r < 4; ++r)
#pragma unroll
        for (int c = 0; c < 8; ++c) o[r][c] = 0.f;

    for (int jt = 0; jt < NTOK / BJ; ++jt) {
        __syncthreads();   // prev iteration fully done with Ks/Vs/Ps
        // stage K transposed
        {
            const int j = tid & 63;
            const int c = tid >> 6;
            const float* srck = &k[base + (size_t)(jt * BJ + j) * DHEAD + c * 32];
#pragma unroll
            for (int u = 0; u < 8; ++u) {
                const float4 t4 = *(const float4*)(srck + u * 4);
                const int d = c * 32 + u * 4;
                Ks[d + 0][j] = t4.x; Ks[d + 1][j] = t4.y; Ks[d + 2][j] = t4.z; Ks[d + 3][j] = t4.w;
            }
        }
        // stage V row-major
        {
            const float* srcv = &v[base + (size_t)(jt * BJ) * DHEAD];
#pragma unroll
            for (int u = 0; u < 8; ++u) {
                const int idx = tid + u * 256;
                const int j  = idx >> 5;
                const int dq = (idx & 31) * 4;
                *(float4*)(&Vs[j][dq]) = *(const float4*)(srcv + (size_t)j * DHEAD + dq);
            }
        }
        __syncthreads();

        // S = Q K'^T   (emb already folded into k)
        float acc[4][4];
#pragma unroll
        for (int r = 0; r < 4; ++r)
#pragma unroll
            for (int c = 0; c < 4; ++c) acc[r][c] = 0.f;
#pragma unroll 8
        for (int d = 0; d < DHEAD; ++d) {
            const float4 q4 = *(const float4*)(&Qs[d][ty * 4]);
            const float4 k4 = *(const float4*)(&Ks[d][tx * 4]);
            acc[0][0] += q4.x * k4.x; acc[0][1] += q4.x * k4.y; acc[0][2] += q4.x * k4.z; acc[0][3] += q4.x * k4.w;
            acc[1][0] += q4.y * k4.x; acc[1][1] += q4.y * k4.y; acc[1][2] += q4.y * k4.z; acc[1][3] += q4.y * k4.w;
            acc[2][0] += q4.z * k4.x; acc[2][1] += q4.z * k4.y; acc[2][2] += q4.z * k4.z; acc[2][3] += q4.z * k4.w;
            acc[3][0] += q4.w * k4.x; acc[3][1] += q4.w * k4.y; acc[3][2] += q4.w * k4.z; acc[3][3] += q4.w * k4.w;
        }

        // online softmax (row groups are 16 contiguous lanes within a wave)
        float tmax[4];
#pragma unroll
        for (int r = 0; r < 4; ++r)
            tmax[r] = fmaxf(fmaxf(acc[r][0], acc[r][1]), fmaxf(acc[r][2], acc[r][3]));
#pragma unroll
        for (int off = 1; off < 16; off <<= 1)
#pragma unroll
            for (int r = 0; r < 4; ++r)
                tmax[r] = fmaxf(tmax[r], __shfl_xor(tmax[r], off));

        float fr[4], sum[4];
#pragma unroll
        for (int r = 0; r < 4; ++r) {
            const float mn = fmaxf(m[r], tmax[r]);
            fr[r] = __expf(m[r] - mn);
            m[r] = mn;
            float s0 = 0.f;
#pragma unroll
            for (int c = 0; c < 4; ++c) {
                const float p = __expf(acc[r][c] - mn);
                acc[r][c] = p;
                s0 += p;
            }
            sum[r] = s0;
        }
#pragma unroll
        for (int off = 1; off < 16; off <<= 1)
#pragma unroll
            for (int r = 0; r < 4; ++r)
                sum[r] += __shfl_xor(sum[r], off);
#pragma unroll
        for (int r = 0; r < 4; ++r) l[r] = l[r] * fr[r] + sum[r];

        // write P transposed [j][i]
#pragma unroll
        for (int r = 0; r < 4; ++r)
#pragma unroll
            for (int c = 0; c < 4; ++c)
                Ps[tx * 4 + c][ty * 4 + r] = acc[r][c];

        // rescale O
#pragma unroll
        for (int r = 0; r < 4; ++r)
#pragma unroll
            for (int c = 0; c < 8; ++c) o[r][c] *= fr[r];

        __syncthreads();   // Ps visible to all

        // O += P V
#pragma unroll 4
        for (int j = 0; j < BJ; ++j) {
            const float4 p4 = *(const float4*)(&Ps[j][ty * 4]);
            const float4 v0 = *(const float4*)(&Vs[j][tx * 4]);
            const float4 v1 = *(const float4*)(&Vs[j][64 + tx * 4]);
            o[0][0] += p4.x * v0.x; o[0][1] += p4.x * v0.y; o[0][2] += p4.x * v0.z; o[0][3] += p4.x * v0.w;
            o[0][4] += p4.x * v1.x; o[0][5] += p4.x * v1.y; o[0][6] += p4.x * v1.z; o[0][7] += p4.x * v1.w;
            o[1][0] += p4.y * v0.x; o[1][1] += p4.y * v0.y; o[1][2] += p4.y * v0.z; o[1][3] += p4.y * v0.w;
            o[1][4] += p4.y * v1.x; o[1][5] += p4.y * v1.y; o[1][6] += p4.y * v1.z; o[1][7] += p4.y * v1.w;
            o[2][0] += p4.z * v0.x; o[2][1] += p4.z * v0.y; o[2][2] += p4.z * v0.z; o[2][3] += p4.z * v0.w;
            o[2][4] += p4.z * v1.x; o[2][5] += p4.z * v1.y; o[2][6] += p4.z * v1.z; o[2][7] += p4.z * v1.w;
            o[3][0] += p4.w * v0.x; o[3][1] += p4.w * v0.y; o[3][2] += p4.w * v0.z; o[3][3] += p4.w * v0.w;
            o[3][4] += p4.w * v1.x; o[3][5] += p4.w * v1.y; o[3][6] += p4.w * v1.z; o[3][7] += p4.w * v1.w;
        }
    }

    // epilogue: normalize, transpose via LDS (reuse Ks as Od[d][i]), coalesced store
    float inv[4];
#pragma unroll
    for (int r = 0; r < 4; ++r) inv[r] = 1.0f / l[r];
#pragma unroll
    for (int r = 0; r < 4; ++r)
#pragma unroll
        for (int c = 0; c < 4; ++c) {
            Ks[tx * 4 + c][ty * 4 + r]      = o[r][c]     * inv[r];
            Ks[64 + tx * 4 + c][ty * 4 + r] = o[r][c + 4] * inv[r];
        }
    __syncthreads();

    const int b = bh >> 2;
    const int h = bh & 3;
    float* dst = &out[((size_t)b * (HEADS * DHEAD) + h * DHEAD) * NTOK + ii];
#pragma unroll
    for (int u = 0; u < 8; ++u) {
        const int idx = tid + u * 256;
        const int d  = idx >> 4;
        const int fq = (idx & 15) * 4;
        const float4 t4 = *(const float4*)(&Ks[d][fq]);
        *(float4*)(dst + (size_t)d * NTOK + fq) = t4;
    }
}

// ---------------------------------------------------------------------------
extern "C" void kernel_launch(void* const* d_in, const int* in_sizes, int n_in,
                              void* d_out, int out_size, void* d_ws, size_t ws_size,
                              hipStream_t stream)
{
    (void)in_sizes; (void)n_in; (void)out_size; (void)ws_size;
    const float* fmap  = (const float*)d_in[0];
    const float* w_qkv = (const float*)d_in[1];
    const float* eh    = (const float*)d_in[2];
    const float* ew    = (const float*)d_in[3];
    float* out = (float*)d_out;

    const size_t per = (size_t)BATCH * HEADS * NTOK * DHEAD;   // 8.39M floats
    float* q = (float*)d_ws;
    float* k = q + per;
    float* v = k + per;

    dim3 g1(OCH / K1_BO, NTOK / K1_BI, BATCH);
    hipLaunchKernelGGL(qkv_kernel, g1, dim3(256), 0, stream, fmap, w_qkv, eh, ew, q, k, v);

    dim3 g2(NTOK / BI, BATCH * HEADS);
    hipLaunchKernelGGL(attn_kernel, g2, dim3(256), 0, stream, q, k, v, out);
}

// Round 8
// 514.599 us; speedup vs baseline: 2.0789x; 2.0789x over previous
//
#include <hip/hip_runtime.h>

#define HEADS 4
#define DHEAD 128
#define DIM   512
#define NTOK  1024     // 32*32
#define BATCH 16
#define OCH   1536     // 3 * HEADS * DHEAD

typedef unsigned short u16;
typedef short bf16x8 __attribute__((ext_vector_type(8)));   // 8 bf16 = 4 VGPR
typedef float f32x4  __attribute__((ext_vector_type(4)));

struct alignas(8) us4 { u16 x, y, z, w; };

static __device__ __forceinline__ u16 f2bf(float f) {
    unsigned int u = __float_as_uint(f);
    u = (u + 0x7FFFu + ((u >> 16) & 1u)) >> 16;   // RNE
    return (u16)u;
}
static __device__ __forceinline__ float bf2f(u16 h) {
    return __uint_as_float(((unsigned int)h) << 16);
}

// ---------------------------------------------------------------------------
// Kernel 1: QKV projection (fp32 GEMM). Epilogue emits:
//   q_hi/q_lo, k_hi/k_lo  bf16 [b][h][i][128]   (q scaled, k += emb(i))
//   vt                    bf16 [b][h][d][i]     (transposed for attn PV)
// ---------------------------------------------------------------------------
#define K1_BO 64
#define K1_BI 64
#define K1_KT 16

__global__ __launch_bounds__(256)
void qkv_kernel(const float* __restrict__ F, const float* __restrict__ W,
                const float* __restrict__ EH, const float* __restrict__ EW,
                u16* __restrict__ qhi, u16* __restrict__ qlo,
                u16* __restrict__ khi, u16* __restrict__ klo,
                u16* __restrict__ vtg)
{
    __shared__ float As[K1_KT][K1_BO + 4];
    __shared__ float Bs[K1_KT][K1_BI + 4];

    const int b  = blockIdx.z;
    const int oo = blockIdx.x * K1_BO;
    const int ii = blockIdx.y * K1_BI;

    const int tid = threadIdx.x;
    const int tx = tid & 15;
    const int ty = tid >> 4;

    float acc[4][4];
#pragma unroll
    for (int r = 0; r < 4; ++r)
#pragma unroll
        for (int c = 0; c < 4; ++c) acc[r][c] = 0.f;

    const int arow = tid >> 2;
    const int ac0  = (tid & 3) * 4;
    const int brow = tid >> 4;
    const int bf0  = (tid & 15) * 4;

    for (int kt = 0; kt < DIM; kt += K1_KT) {
        const float4 w4 = *(const float4*)(&W[(size_t)(oo + arow) * DIM + kt + ac0]);
        const float4 f4 = *(const float4*)(&F[((size_t)b * DIM + kt + brow) * NTOK + ii + bf0]);
        As[ac0 + 0][arow] = w4.x;
        As[ac0 + 1][arow] = w4.y;
        As[ac0 + 2][arow] = w4.z;
        As[ac0 + 3][arow] = w4.w;
        *(float4*)(&Bs[brow][bf0]) = f4;
        __syncthreads();
#pragma unroll
        for (int kk = 0; kk < K1_KT; ++kk) {
            const float4 a4 = *(const float4*)(&As[kk][tx * 4]);
            const float4 b4 = *(const float4*)(&Bs[kk][ty * 4]);
            acc[0][0] += b4.x * a4.x; acc[0][1] += b4.x * a4.y; acc[0][2] += b4.x * a4.z; acc[0][3] += b4.x * a4.w;
            acc[1][0] += b4.y * a4.x; acc[1][1] += b4.y * a4.y; acc[1][2] += b4.y * a4.z; acc[1][3] += b4.y * a4.w;
            acc[2][0] += b4.z * a4.x; acc[2][1] += b4.z * a4.y; acc[2][2] += b4.z * a4.z; acc[2][3] += b4.z * a4.w;
            acc[3][0] += b4.w * a4.x; acc[3][1] += b4.w * a4.y; acc[3][2] += b4.w * a4.z; acc[3][3] += b4.w * a4.w;
        }
        __syncthreads();
    }

    const int ob = oo + tx * 4;      // s/h/d0 uniform per block (oo % 64 == 0 within a 128-block)
    const int s  = ob >> 9;
    const int h  = (ob >> 7) & 3;
    const int d0 = ob & 127;
    const int bh = b * HEADS + h;
    const float scale = 0.08838834764831845f;   // 128^-0.5

    if (s == 2) {
        // vt[bh][d][i]
#pragma unroll
        for (int r = 0; r < 4; ++r) {
            const int i = ii + ty * 4 + r;
#pragma unroll
            for (int c = 0; c < 4; ++c)
                vtg[((size_t)bh * DHEAD + d0 + c) * NTOK + i] = f2bf(acc[r][c]);
        }
    } else {
        u16* hi = s ? khi : qhi;
        u16* lo = s ? klo : qlo;
        const size_t rowbase = (size_t)bh * NTOK;
#pragma unroll
        for (int r = 0; r < 4; ++r) {
            const int i = ii + ty * 4 + r;
            float v0 = acc[r][0], v1 = acc[r][1], v2 = acc[r][2], v3 = acc[r][3];
            if (s == 0) {
                v0 *= scale; v1 *= scale; v2 *= scale; v3 *= scale;
            } else {
                const float4 eh = *(const float4*)(&EH[(i >> 5) * DHEAD + d0]);
                const float4 ew = *(const float4*)(&EW[(i & 31) * DHEAD + d0]);
                v0 += eh.x + ew.x; v1 += eh.y + ew.y; v2 += eh.z + ew.z; v3 += eh.w + ew.w;
            }
            us4 H, L;
            H.x = f2bf(v0); L.x = f2bf(v0 - bf2f(H.x));
            H.y = f2bf(v1); L.y = f2bf(v1 - bf2f(H.y));
            H.z = f2bf(v2); L.z = f2bf(v2 - bf2f(H.z));
            H.w = f2bf(v3); L.w = f2bf(v3 - bf2f(H.w));
            *(us4*)&hi[(rowbase + i) * DHEAD + d0] = H;
            *(us4*)&lo[(rowbase + i) * DHEAD + d0] = L;
        }
    }
}

// ---------------------------------------------------------------------------
// Kernel 2: MFMA flash attention.
// 256 thr = 4 waves; Q-tile 64 (16 rows/wave, Q hi/lo in regs); KV-tile 64.
// sim = qh*kh + qh*kl + ql*kh (split-bf16, fp32-grade); PV plain bf16.
// K LDS [64][128] + V LDS [128][64] XOR-swizzled (T2); P via per-wave LDS.
// ---------------------------------------------------------------------------
#define QB 64
#define KB 64

__global__ __launch_bounds__(256, 2)
void attn_mfma(const u16* __restrict__ qh, const u16* __restrict__ ql,
               const u16* __restrict__ kh, const u16* __restrict__ kl,
               const u16* __restrict__ vtg, float* __restrict__ out)
{
    __shared__ u16 smem[28672];            // 57344 B -> 2 blocks/CU
    u16* Kh = smem;                        // [64][128] swizzled
    u16* Kl = smem + 8192;
    u16* Vt = smem + 16384;                // [128][64] swizzled
    u16* Pl = smem + 24576;                // 4 waves x [16][64] swizzled
    float* Od = (float*)smem;              // epilogue reuse [128][72]

    const int tid  = threadIdx.x;
    const int lane = tid & 63;
    const int wave = tid >> 6;
    const int l15  = lane & 15;
    const int lg   = lane >> 4;

    const int ii = blockIdx.x * QB;
    const int bh = blockIdx.y;
    const size_t base = (size_t)bh * NTOK * DHEAD;   // also vt base (128*1024)

    // Q fragments in registers: row = l15 (wave's 16 rows), k = kc*32 + lg*8
    bf16x8 qfh[4], qfl[4];
    {
        const size_t qoff = base + (size_t)(ii + wave * 16 + l15) * DHEAD + lg * 8;
#pragma unroll
        for (int kc = 0; kc < 4; ++kc) {
            qfh[kc] = *(const bf16x8*)(qh + qoff + kc * 32);
            qfl[kc] = *(const bf16x8*)(ql + qoff + kc * 32);
        }
    }

    f32x4 o[8];
#pragma unroll
    for (int n = 0; n < 8; ++n) { o[n][0] = 0.f; o[n][1] = 0.f; o[n][2] = 0.f; o[n][3] = 0.f; }
    float mrow[4], lrow[4];
#pragma unroll
    for (int r = 0; r < 4; ++r) { mrow[r] = -3.0e38f; lrow[r] = 0.f; }

    for (int jt = 0; jt < NTOK / KB; ++jt) {
        __syncthreads();                   // prev iter done reading K/V LDS
        // stage K hi/lo (swizzled rows of 128 bf16)
#pragma unroll
        for (int u = 0; u < 4; ++u) {
            const int idx = tid + 256 * u;
            const int j  = idx >> 4;
            const int dc = (idx & 15) * 8;
            const size_t g = base + (size_t)(jt * KB + j) * DHEAD + dc;
            const int ld = j * DHEAD + (dc ^ ((j & 7) << 3));
            *(bf16x8*)&Kh[ld] = *(const bf16x8*)(kh + g);
            *(bf16x8*)&Kl[ld] = *(const bf16x8*)(kl + g);
        }
        // stage Vt (already [d][i] in global; swizzled rows of 64 bf16)
#pragma unroll
        for (int u = 0; u < 4; ++u) {
            const int idx = tid + 256 * u;
            const int d  = idx >> 3;
            const int jc = (idx & 7) * 8;
            const size_t g = base + (size_t)d * NTOK + jt * KB + jc;
            *(bf16x8*)&Vt[d * KB + (jc ^ ((d & 7) << 3))] = *(const bf16x8*)(vtg + g);
        }
        __syncthreads();

        // S = Q K'^T  (split bf16: 3 MFMA per (n,kc))
        f32x4 s[4];
#pragma unroll
        for (int n = 0; n < 4; ++n) {
            f32x4 acc = {0.f, 0.f, 0.f, 0.f};
            const int j  = n * 16 + l15;
            const int ro = j * DHEAD;
            const int sw = (j & 7) << 3;
#pragma unroll
            for (int kc = 0; kc < 4; ++kc) {
                const int off = ro + ((kc * 32 + lg * 8) ^ sw);
                const bf16x8 kb = *(const bf16x8*)&Kh[off];
                const bf16x8 lb = *(const bf16x8*)&Kl[off];
                acc = __builtin_amdgcn_mfma_f32_16x16x32_bf16(qfh[kc], kb, acc, 0, 0, 0);
                acc = __builtin_amdgcn_mfma_f32_16x16x32_bf16(qfh[kc], lb, acc, 0, 0, 0);
                acc = __builtin_amdgcn_mfma_f32_16x16x32_bf16(qfl[kc], kb, acc, 0, 0, 0);
            }
            s[n] = acc;
        }

        // online softmax; D layout: col j = n*16 + l15, row = lg*4 + r
        float tmax[4];
#pragma unroll
        for (int r = 0; r < 4; ++r)
            tmax[r] = fmaxf(fmaxf(s[0][r], s[1][r]), fmaxf(s[2][r], s[3][r]));
#pragma unroll
        for (int off = 1; off < 16; off <<= 1)
#pragma unroll
            for (int r = 0; r < 4; ++r)
                tmax[r] = fmaxf(tmax[r], __shfl_xor(tmax[r], off));

        float fr[4], psum[4];
#pragma unroll
        for (int r = 0; r < 4; ++r) {
            const float mn = fmaxf(mrow[r], tmax[r]);
            fr[r] = __expf(mrow[r] - mn);
            mrow[r] = mn;
            psum[r] = 0.f;
        }
        const int pbase = wave * 1024;
#pragma unroll
        for (int n = 0; n < 4; ++n)
#pragma unroll
            for (int r = 0; r < 4; ++r) {
                const float p = __expf(s[n][r] - mrow[r]);
                psum[r] += p;
                const int row = lg * 4 + r;
                Pl[pbase + row * KB + ((n * 16 + l15) ^ ((row & 7) << 3))] = f2bf(p);
            }
#pragma unroll
        for (int off = 1; off < 16; off <<= 1)
#pragma unroll
            for (int r = 0; r < 4; ++r)
                psum[r] += __shfl_xor(psum[r], off);
#pragma unroll
        for (int r = 0; r < 4; ++r) lrow[r] = lrow[r] * fr[r] + psum[r];
#pragma unroll
        for (int n = 0; n < 8; ++n)
#pragma unroll
            for (int r = 0; r < 4; ++r) o[n][r] *= fr[r];

        // PV: A = P (row=l15, k j = kc*32+lg*8), B = Vt (col d = nd*16+l15)
        const bf16x8 pf0 = *(const bf16x8*)&Pl[pbase + l15 * KB + ((lg * 8) ^ ((l15 & 7) << 3))];
        const bf16x8 pf1 = *(const bf16x8*)&Pl[pbase + l15 * KB + ((32 + lg * 8) ^ ((l15 & 7) << 3))];
#pragma unroll
        for (int nd = 0; nd < 8; ++nd) {
            const int d  = nd * 16 + l15;
            const int vo = d * KB;
            const int sw = (d & 7) << 3;
            o[nd] = __builtin_amdgcn_mfma_f32_16x16x32_bf16(
                        pf0, *(const bf16x8*)&Vt[vo + ((lg * 8) ^ sw)], o[nd], 0, 0, 0);
            o[nd] = __builtin_amdgcn_mfma_f32_16x16x32_bf16(
                        pf1, *(const bf16x8*)&Vt[vo + ((32 + lg * 8) ^ sw)], o[nd], 0, 0, 0);
        }
    }

    // epilogue: normalize, transpose via LDS, coalesced store out[b][h*128+d][i]
    __syncthreads();
    float invl[4];
#pragma unroll
    for (int r = 0; r < 4; ++r) invl[r] = 1.0f / lrow[r];
#pragma unroll
    for (int nd = 0; nd < 8; ++nd)
#pragma unroll
        for (int r = 0; r < 4; ++r)
            Od[(nd * 16 + l15) * 72 + wave * 16 + lg * 4 + r] = o[nd][r] * invl[r];
    __syncthreads();

    const int b = bh >> 2, h = bh & 3;
    float* dst = out + ((size_t)b * 512 + h * DHEAD) * NTOK + ii;
#pragma unroll
    for (int u = 0; u < 4; ++u) {
        const int idx = tid + 256 * u;
        const int d  = idx >> 3;
        const int jc = (idx & 7) * 8;
        *(float4*)(dst + (size_t)d * NTOK + jc)     = *(const float4*)&Od[d * 72 + jc];
        *(float4*)(dst + (size_t)d * NTOK + jc + 4) = *(const float4*)&Od[d * 72 + jc + 4];
    }
}

// ---------------------------------------------------------------------------
extern "C" void kernel_launch(void* const* d_in, const int* in_sizes, int n_in,
                              void* d_out, int out_size, void* d_ws, size_t ws_size,
                              hipStream_t stream)
{
    (void)in_sizes; (void)n_in; (void)out_size; (void)ws_size;
    const float* fmap  = (const float*)d_in[0];
    const float* w_qkv = (const float*)d_in[1];
    const float* eh    = (const float*)d_in[2];
    const float* ew    = (const float*)d_in[3];
    float* out = (float*)d_out;

    const size_t per = (size_t)BATCH * HEADS * NTOK * DHEAD;   // 8.39M elems
    u16* qhi = (u16*)d_ws;
    u16* qlo = qhi + per;
    u16* khi = qlo + per;
    u16* klo = khi + per;
    u16* vtg = klo + per;                                      // 5 x 16.8 MB = 84 MB

    dim3 g1(OCH / K1_BO, NTOK / K1_BI, BATCH);
    hipLaunchKernelGGL(qkv_kernel, g1, dim3(256), 0, stream,
                       fmap, w_qkv, eh, ew, qhi, qlo, khi, klo, vtg);

    dim3 g2(NTOK / QB, BATCH * HEADS);
    hipLaunchKernelGGL(attn_mfma, g2, dim3(256), 0, stream,
                       qhi, qlo, khi, klo, vtg, out);
}

// Round 9
// 307.296 us; speedup vs baseline: 3.4814x; 1.6746x over previous
//
#include <hip/hip_runtime.h>

#define HEADS 4
#define DHEAD 128
#define DIM   512
#define NTOK  1024     // 32*32
#define BATCH 16
#define OCH   1536     // 3 * HEADS * DHEAD

typedef unsigned short u16;
typedef short bf16x8 __attribute__((ext_vector_type(8)));   // 8 bf16 = 4 VGPR
typedef float f32x4  __attribute__((ext_vector_type(4)));

struct alignas(8) us4 { u16 x, y, z, w; };

static __device__ __forceinline__ u16 f2bf(float f) {
    unsigned int u = __float_as_uint(f);
    u = (u + 0x7FFFu + ((u >> 16) & 1u)) >> 16;   // RNE
    return (u16)u;
}
static __device__ __forceinline__ float bf2f(u16 h) {
    return __uint_as_float(((unsigned int)h) << 16);
}

// ---------------------------------------------------------------------------
// Prep 1: Ft = F transposed+converted: [b][n=1024][c=512] bf16 hi/lo.
// 32x32 LDS tile transpose per block.
// ---------------------------------------------------------------------------
__global__ __launch_bounds__(256)
void prep_ft(const float* __restrict__ F, u16* __restrict__ fthi, u16* __restrict__ ftlo)
{
    __shared__ float T[32][33];
    const int n0 = blockIdx.x * 32;
    const int c0 = blockIdx.y * 32;
    const int b  = blockIdx.z;
    const int tid = threadIdx.x;

    {
        const int c  = tid >> 3;
        const int n4 = (tid & 7) * 4;
        const float4 f4 = *(const float4*)(&F[((size_t)b * DIM + c0 + c) * NTOK + n0 + n4]);
        T[c][n4 + 0] = f4.x; T[c][n4 + 1] = f4.y; T[c][n4 + 2] = f4.z; T[c][n4 + 3] = f4.w;
    }
    __syncthreads();
    {
        const int n  = tid >> 3;
        const int c4 = (tid & 7) * 4;
        us4 H, L;
        float v0 = T[c4 + 0][n], v1 = T[c4 + 1][n], v2 = T[c4 + 2][n], v3 = T[c4 + 3][n];
        H.x = f2bf(v0); L.x = f2bf(v0 - bf2f(H.x));
        H.y = f2bf(v1); L.y = f2bf(v1 - bf2f(H.y));
        H.z = f2bf(v2); L.z = f2bf(v2 - bf2f(H.z));
        H.w = f2bf(v3); L.w = f2bf(v3 - bf2f(H.w));
        const size_t o = ((size_t)b * NTOK + n0 + n) * DIM + c0 + c4;
        *(us4*)&fthi[o] = H;
        *(us4*)&ftlo[o] = L;
    }
}

// ---------------------------------------------------------------------------
// Prep 2: Wb = W converted: [o=1536][c=512] bf16 hi/lo (layout unchanged).
// ---------------------------------------------------------------------------
__global__ __launch_bounds__(256)
void prep_w(const float* __restrict__ W, u16* __restrict__ wbhi, u16* __restrict__ wblo)
{
    const size_t idx = ((size_t)blockIdx.x * 256 + threadIdx.x) * 8;
    const float4 a = *(const float4*)(&W[idx]);
    const float4 b = *(const float4*)(&W[idx + 4]);
    float v[8] = {a.x, a.y, a.z, a.w, b.x, b.y, b.z, b.w};
    u16 H[8], L[8];
#pragma unroll
    for (int j = 0; j < 8; ++j) {
        H[j] = f2bf(v[j]);
        L[j] = f2bf(v[j] - bf2f(H[j]));
    }
    *(bf16x8*)&wbhi[idx] = *(bf16x8*)H;
    *(bf16x8*)&wblo[idx] = *(bf16x8*)L;
}

// ---------------------------------------------------------------------------
// Kernel 1: QKV projection, split-bf16 MFMA GEMM.
// O[o][n] = sum_c W[o][c] F[c][n]; A = Ft[n][c] (M=64 tokens), B^T = Wb[o][c]
// (N=64 o), K-step 64, 4 waves in 2x2, 3-MFMA split: Ah*Bh + Ah*Bl + Al*Bh.
// Epilogue via LDS: q/k hi+lo (+scale/emb), vt transposed. Same staging /
// swizzle / fragment patterns as the validated attn kernel.
// ---------------------------------------------------------------------------
__global__ __launch_bounds__(256)
void qkv_mfma(const u16* __restrict__ fthi, const u16* __restrict__ ftlo,
              const u16* __restrict__ wbhi, const u16* __restrict__ wblo,
              const float* __restrict__ EH, const float* __restrict__ EW,
              u16* __restrict__ qhi, u16* __restrict__ qlo,
              u16* __restrict__ khi, u16* __restrict__ klo,
              u16* __restrict__ vtg)
{
    __shared__ u16 smem[16384];            // 32 KB
    u16* Ah = smem;                        // [64][64] swizzled (token x k)
    u16* Al = smem + 4096;
    u16* Bh = smem + 8192;                 // [64][64] swizzled (o x k)
    u16* Bl = smem + 12288;
    float* Od = (float*)smem;              // epilogue reuse [64][68] f32 (17.4 KB)

    const int tid  = threadIdx.x;
    const int lane = tid & 63;
    const int wave = tid >> 6;
    const int l15  = lane & 15;
    const int lg   = lane >> 4;
    const int wm   = wave >> 1;            // token half (0,1)
    const int wn   = wave & 1;             // o half (0,1)

    const int ii = blockIdx.x * 64;        // token tile
    const int oo = blockIdx.y * 64;        // o tile
    const int b  = blockIdx.z;
    const size_t fbase = (size_t)b * NTOK * DIM;

    f32x4 acc[2][2];
#pragma unroll
    for (int mf = 0; mf < 2; ++mf)
#pragma unroll
        for (int nf = 0; nf < 2; ++nf) { acc[mf][nf][0] = 0.f; acc[mf][nf][1] = 0.f; acc[mf][nf][2] = 0.f; acc[mf][nf][3] = 0.f; }

    for (int kt = 0; kt < DIM; kt += 64) {
        __syncthreads();
#pragma unroll
        for (int u = 0; u < 2; ++u) {
            const int idx = tid + 256 * u;
            const int j  = idx >> 3;
            const int dc = (idx & 7) * 8;
            const int ld = j * 64 + (dc ^ ((j & 7) << 3));
            const size_t ga = fbase + (size_t)(ii + j) * DIM + kt + dc;
            const size_t gb = (size_t)(oo + j) * DIM + kt + dc;
            *(bf16x8*)&Ah[ld] = *(const bf16x8*)(fthi + ga);
            *(bf16x8*)&Al[ld] = *(const bf16x8*)(ftlo + ga);
            *(bf16x8*)&Bh[ld] = *(const bf16x8*)(wbhi + gb);
            *(bf16x8*)&Bl[ld] = *(const bf16x8*)(wblo + gb);
        }
        __syncthreads();

#pragma unroll
        for (int kc = 0; kc < 2; ++kc) {
            const int ko = kc * 32 + lg * 8;
            bf16x8 af_h[2], af_l[2], bf_h[2], bf_l[2];
#pragma unroll
            for (int mf = 0; mf < 2; ++mf) {
                const int ar = wm * 32 + mf * 16 + l15;
                const int off = ar * 64 + (ko ^ ((ar & 7) << 3));
                af_h[mf] = *(const bf16x8*)&Ah[off];
                af_l[mf] = *(const bf16x8*)&Al[off];
            }
#pragma unroll
            for (int nf = 0; nf < 2; ++nf) {
                const int br = wn * 32 + nf * 16 + l15;
                const int off = br * 64 + (ko ^ ((br & 7) << 3));
                bf_h[nf] = *(const bf16x8*)&Bh[off];
                bf_l[nf] = *(const bf16x8*)&Bl[off];
            }
#pragma unroll
            for (int mf = 0; mf < 2; ++mf)
#pragma unroll
                for (int nf = 0; nf < 2; ++nf) {
                    acc[mf][nf] = __builtin_amdgcn_mfma_f32_16x16x32_bf16(af_h[mf], bf_h[nf], acc[mf][nf], 0, 0, 0);
                    acc[mf][nf] = __builtin_amdgcn_mfma_f32_16x16x32_bf16(af_h[mf], bf_l[nf], acc[mf][nf], 0, 0, 0);
                    acc[mf][nf] = __builtin_amdgcn_mfma_f32_16x16x32_bf16(af_l[mf], bf_h[nf], acc[mf][nf], 0, 0, 0);
                }
        }
    }

    __syncthreads();                       // done reading staging LDS
    // D layout (validated): col = l15 (o within frag), row = lg*4 + r (token)
#pragma unroll
    for (int mf = 0; mf < 2; ++mf)
#pragma unroll
        for (int nf = 0; nf < 2; ++nf)
#pragma unroll
            for (int r = 0; r < 4; ++r)
                Od[(wm * 32 + mf * 16 + lg * 4 + r) * 68 + wn * 32 + nf * 16 + l15] = acc[mf][nf][r];
    __syncthreads();

    const int s  = oo >> 9;
    const int h  = (oo >> 7) & 3;
    const int d0 = oo & 127;
    const int bh = b * HEADS + h;
    const float scale = 0.08838834764831845f;   // 128^-0.5

    if (s == 2) {
        // vt[bh][d][i]: transpose read from Od columns, coalesced bf16x8 store
#pragma unroll
        for (int u = 0; u < 2; ++u) {
            const int idx = tid + 256 * u;
            const int dr = idx >> 3;          // o within tile -> d = d0+dr
            const int tc = (idx & 7) * 8;     // token chunk
            u16 P[8];
#pragma unroll
            for (int j = 0; j < 8; ++j)
                P[j] = f2bf(Od[(tc + j) * 68 + dr]);
            *(bf16x8*)&vtg[((size_t)bh * DHEAD + d0 + dr) * NTOK + ii + tc] = *(bf16x8*)P;
        }
    } else {
        u16* hi = s ? khi : qhi;
        u16* lo = s ? klo : qlo;
#pragma unroll
        for (int u = 0; u < 2; ++u) {
            const int idx = tid + 256 * u;
            const int tr = idx >> 3;
            const int dc = (idx & 7) * 8;
            const int i  = ii + tr;
            float v[8];
            const float4 p0 = *(const float4*)&Od[tr * 68 + dc];
            const float4 p1 = *(const float4*)&Od[tr * 68 + dc + 4];
            v[0] = p0.x; v[1] = p0.y; v[2] = p0.z; v[3] = p0.w;
            v[4] = p1.x; v[5] = p1.y; v[6] = p1.z; v[7] = p1.w;
            if (s == 0) {
#pragma unroll
                for (int j = 0; j < 8; ++j) v[j] *= scale;
            } else {
                const float* eh = &EH[(i >> 5) * DHEAD + d0 + dc];
                const float* ew = &EW[(i & 31) * DHEAD + d0 + dc];
                const float4 e0 = *(const float4*)eh, e1 = *(const float4*)(eh + 4);
                const float4 w0 = *(const float4*)ew, w1 = *(const float4*)(ew + 4);
                v[0] += e0.x + w0.x; v[1] += e0.y + w0.y; v[2] += e0.z + w0.z; v[3] += e0.w + w0.w;
                v[4] += e1.x + w1.x; v[5] += e1.y + w1.y; v[6] += e1.z + w1.z; v[7] += e1.w + w1.w;
            }
            u16 H[8], L[8];
#pragma unroll
            for (int j = 0; j < 8; ++j) {
                H[j] = f2bf(v[j]);
                L[j] = f2bf(v[j] - bf2f(H[j]));
            }
            const size_t o = ((size_t)bh * NTOK + i) * DHEAD + d0 + dc;
            *(bf16x8*)&hi[o] = *(bf16x8*)H;
            *(bf16x8*)&lo[o] = *(bf16x8*)L;
        }
    }
}

// ---------------------------------------------------------------------------
// Kernel 2: MFMA flash attention (VALIDATED round 8 — unchanged).
// ---------------------------------------------------------------------------
#define QB 64
#define KB 64

__global__ __launch_bounds__(256, 2)
void attn_mfma(const u16* __restrict__ qh, const u16* __restrict__ ql,
               const u16* __restrict__ kh, const u16* __restrict__ kl,
               const u16* __restrict__ vtg, float* __restrict__ out)
{
    __shared__ u16 smem[28672];            // 57344 B -> 2 blocks/CU
    u16* Kh = smem;                        // [64][128] swizzled
    u16* Kl = smem + 8192;
    u16* Vt = smem + 16384;                // [128][64] swizzled
    u16* Pl = smem + 24576;                // 4 waves x [16][64] swizzled
    float* Od = (float*)smem;              // epilogue reuse [128][72]

    const int tid  = threadIdx.x;
    const int lane = tid & 63;
    const int wave = tid >> 6;
    const int l15  = lane & 15;
    const int lg   = lane >> 4;

    const int ii = blockIdx.x * QB;
    const int bh = blockIdx.y;
    const size_t base = (size_t)bh * NTOK * DHEAD;   // also vt base (128*1024)

    bf16x8 qfh[4], qfl[4];
    {
        const size_t qoff = base + (size_t)(ii + wave * 16 + l15) * DHEAD + lg * 8;
#pragma unroll
        for (int kc = 0; kc < 4; ++kc) {
            qfh[kc] = *(const bf16x8*)(qh + qoff + kc * 32);
            qfl[kc] = *(const bf16x8*)(ql + qoff + kc * 32);
        }
    }

    f32x4 o[8];
#pragma unroll
    for (int n = 0; n < 8; ++n) { o[n][0] = 0.f; o[n][1] = 0.f; o[n][2] = 0.f; o[n][3] = 0.f; }
    float mrow[4], lrow[4];
#pragma unroll
    for (int r = 0; r < 4; ++r) { mrow[r] = -3.0e38f; lrow[r] = 0.f; }

    for (int jt = 0; jt < NTOK / KB; ++jt) {
        __syncthreads();
#pragma unroll
        for (int u = 0; u < 4; ++u) {
            const int idx = tid + 256 * u;
            const int j  = idx >> 4;
            const int dc = (idx & 15) * 8;
            const size_t g = base + (size_t)(jt * KB + j) * DHEAD + dc;
            const int ld = j * DHEAD + (dc ^ ((j & 7) << 3));
            *(bf16x8*)&Kh[ld] = *(const bf16x8*)(kh + g);
            *(bf16x8*)&Kl[ld] = *(const bf16x8*)(kl + g);
        }
#pragma unroll
        for (int u = 0; u < 4; ++u) {
            const int idx = tid + 256 * u;
            const int d  = idx >> 3;
            const int jc = (idx & 7) * 8;
            const size_t g = base + (size_t)d * NTOK + jt * KB + jc;
            *(bf16x8*)&Vt[d * KB + (jc ^ ((d & 7) << 3))] = *(const bf16x8*)(vtg + g);
        }
        __syncthreads();

        f32x4 s[4];
#pragma unroll
        for (int n = 0; n < 4; ++n) {
            f32x4 acc = {0.f, 0.f, 0.f, 0.f};
            const int j  = n * 16 + l15;
            const int ro = j * DHEAD;
            const int sw = (j & 7) << 3;
#pragma unroll
            for (int kc = 0; kc < 4; ++kc) {
                const int off = ro + ((kc * 32 + lg * 8) ^ sw);
                const bf16x8 kb = *(const bf16x8*)&Kh[off];
                const bf16x8 lb = *(const bf16x8*)&Kl[off];
                acc = __builtin_amdgcn_mfma_f32_16x16x32_bf16(qfh[kc], kb, acc, 0, 0, 0);
                acc = __builtin_amdgcn_mfma_f32_16x16x32_bf16(qfh[kc], lb, acc, 0, 0, 0);
                acc = __builtin_amdgcn_mfma_f32_16x16x32_bf16(qfl[kc], kb, acc, 0, 0, 0);
            }
            s[n] = acc;
        }

        float tmax[4];
#pragma unroll
        for (int r = 0; r < 4; ++r)
            tmax[r] = fmaxf(fmaxf(s[0][r], s[1][r]), fmaxf(s[2][r], s[3][r]));
#pragma unroll
        for (int off = 1; off < 16; off <<= 1)
#pragma unroll
            for (int r = 0; r < 4; ++r)
                tmax[r] = fmaxf(tmax[r], __shfl_xor(tmax[r], off));

        float fr[4], psum[4];
#pragma unroll
        for (int r = 0; r < 4; ++r) {
            const float mn = fmaxf(mrow[r], tmax[r]);
            fr[r] = __expf(mrow[r] - mn);
            mrow[r] = mn;
            psum[r] = 0.f;
        }
        const int pbase = wave * 1024;
#pragma unroll
        for (int n = 0; n < 4; ++n)
#pragma unroll
            for (int r = 0; r < 4; ++r) {
                const float p = __expf(s[n][r] - mrow[r]);
                psum[r] += p;
                const int row = lg * 4 + r;
                Pl[pbase + row * KB + ((n * 16 + l15) ^ ((row & 7) << 3))] = f2bf(p);
            }
#pragma unroll
        for (int off = 1; off < 16; off <<= 1)
#pragma unroll
            for (int r = 0; r < 4; ++r)
                psum[r] += __shfl_xor(psum[r], off);
#pragma unroll
        for (int r = 0; r < 4; ++r) lrow[r] = lrow[r] * fr[r] + psum[r];
#pragma unroll
        for (int n = 0; n < 8; ++n)
#pragma unroll
            for (int r = 0; r < 4; ++r) o[n][r] *= fr[r];

        const bf16x8 pf0 = *(const bf16x8*)&Pl[pbase + l15 * KB + ((lg * 8) ^ ((l15 & 7) << 3))];
        const bf16x8 pf1 = *(const bf16x8*)&Pl[pbase + l15 * KB + ((32 + lg * 8) ^ ((l15 & 7) << 3))];
#pragma unroll
        for (int nd = 0; nd < 8; ++nd) {
            const int d  = nd * 16 + l15;
            const int vo = d * KB;
            const int sw = (d & 7) << 3;
            o[nd] = __builtin_amdgcn_mfma_f32_16x16x32_bf16(
                        pf0, *(const bf16x8*)&Vt[vo + ((lg * 8) ^ sw)], o[nd], 0, 0, 0);
            o[nd] = __builtin_amdgcn_mfma_f32_16x16x32_bf16(
                        pf1, *(const bf16x8*)&Vt[vo + ((32 + lg * 8) ^ sw)], o[nd], 0, 0, 0);
        }
    }

    __syncthreads();
    float invl[4];
#pragma unroll
    for (int r = 0; r < 4; ++r) invl[r] = 1.0f / lrow[r];
#pragma unroll
    for (int nd = 0; nd < 8; ++nd)
#pragma unroll
        for (int r = 0; r < 4; ++r)
            Od[(nd * 16 + l15) * 72 + wave * 16 + lg * 4 + r] = o[nd][r] * invl[r];
    __syncthreads();

    const int b = bh >> 2, h = bh & 3;
    float* dst = out + ((size_t)b * 512 + h * DHEAD) * NTOK + ii;
#pragma unroll
    for (int u = 0; u < 4; ++u) {
        const int idx = tid + 256 * u;
        const int d  = idx >> 3;
        const int jc = (idx & 7) * 8;
        *(float4*)(dst + (size_t)d * NTOK + jc)     = *(const float4*)&Od[d * 72 + jc];
        *(float4*)(dst + (size_t)d * NTOK + jc + 4) = *(const float4*)&Od[d * 72 + jc + 4];
    }
}

// ---------------------------------------------------------------------------
extern "C" void kernel_launch(void* const* d_in, const int* in_sizes, int n_in,
                              void* d_out, int out_size, void* d_ws, size_t ws_size,
                              hipStream_t stream)
{
    (void)in_sizes; (void)n_in; (void)out_size; (void)ws_size;
    const float* fmap  = (const float*)d_in[0];
    const float* w_qkv = (const float*)d_in[1];
    const float* eh    = (const float*)d_in[2];
    const float* ew    = (const float*)d_in[3];
    float* out = (float*)d_out;

    const size_t per = (size_t)BATCH * HEADS * NTOK * DHEAD;   // 8.39M elems
    u16* qhi  = (u16*)d_ws;
    u16* qlo  = qhi + per;
    u16* khi  = qlo + per;
    u16* klo  = khi + per;
    u16* vtg  = klo + per;
    u16* fthi = vtg + per;        // [b][n][c] 8.39M
    u16* ftlo = fthi + per;
    u16* wbhi = ftlo + per;       // 1536*512
    u16* wblo = wbhi + (size_t)OCH * DIM;   // total ~120.6 MB

    hipLaunchKernelGGL(prep_ft, dim3(NTOK / 32, DIM / 32, BATCH), dim3(256), 0, stream,
                       fmap, fthi, ftlo);
    hipLaunchKernelGGL(prep_w, dim3((OCH * DIM) / (256 * 8)), dim3(256), 0, stream,
                       w_qkv, wbhi, wblo);
    hipLaunchKernelGGL(qkv_mfma, dim3(NTOK / 64, OCH / 64, BATCH), dim3(256), 0, stream,
                       fthi, ftlo, wbhi, wblo, eh, ew, qhi, qlo, khi, klo, vtg);
    hipLaunchKernelGGL(attn_mfma, dim3(NTOK / QB, BATCH * HEADS), dim3(256), 0, stream,
                       qhi, qlo, khi, klo, vtg, out);
}

// Round 10
// 301.378 us; speedup vs baseline: 3.5498x; 1.0196x over previous
//
#include <hip/hip_runtime.h>

#define HEADS 4
#define DHEAD 128
#define DIM   512
#define NTOK  1024     // 32*32
#define BATCH 16
#define OCH   1536     // 3 * HEADS * DHEAD

typedef unsigned short u16;
typedef short bf16x8 __attribute__((ext_vector_type(8)));   // 8 bf16 = 4 VGPR
typedef float f32x4  __attribute__((ext_vector_type(4)));

struct alignas(8) us4 { u16 x, y, z, w; };

static __device__ __forceinline__ u16 f2bf(float f) {
    unsigned int u = __float_as_uint(f);
    u = (u + 0x7FFFu + ((u >> 16) & 1u)) >> 16;   // RNE
    return (u16)u;
}
static __device__ __forceinline__ float bf2f(u16 h) {
    return __uint_as_float(((unsigned int)h) << 16);
}

// ---------------------------------------------------------------------------
// Prep 1: Ft = F transposed+converted: [b][n=1024][c=512] bf16 hi/lo.
// ---------------------------------------------------------------------------
__global__ __launch_bounds__(256)
void prep_ft(const float* __restrict__ F, u16* __restrict__ fthi, u16* __restrict__ ftlo)
{
    __shared__ float T[32][33];
    const int n0 = blockIdx.x * 32;
    const int c0 = blockIdx.y * 32;
    const int b  = blockIdx.z;
    const int tid = threadIdx.x;

    {
        const int c  = tid >> 3;
        const int n4 = (tid & 7) * 4;
        const float4 f4 = *(const float4*)(&F[((size_t)b * DIM + c0 + c) * NTOK + n0 + n4]);
        T[c][n4 + 0] = f4.x; T[c][n4 + 1] = f4.y; T[c][n4 + 2] = f4.z; T[c][n4 + 3] = f4.w;
    }
    __syncthreads();
    {
        const int n  = tid >> 3;
        const int c4 = (tid & 7) * 4;
        us4 H, L;
        float v0 = T[c4 + 0][n], v1 = T[c4 + 1][n], v2 = T[c4 + 2][n], v3 = T[c4 + 3][n];
        H.x = f2bf(v0); L.x = f2bf(v0 - bf2f(H.x));
        H.y = f2bf(v1); L.y = f2bf(v1 - bf2f(H.y));
        H.z = f2bf(v2); L.z = f2bf(v2 - bf2f(H.z));
        H.w = f2bf(v3); L.w = f2bf(v3 - bf2f(H.w));
        const size_t o = ((size_t)b * NTOK + n0 + n) * DIM + c0 + c4;
        *(us4*)&fthi[o] = H;
        *(us4*)&ftlo[o] = L;
    }
}

// ---------------------------------------------------------------------------
// Prep 2: Wb = W converted: [o=1536][c=512] bf16 hi/lo.
// ---------------------------------------------------------------------------
__global__ __launch_bounds__(256)
void prep_w(const float* __restrict__ W, u16* __restrict__ wbhi, u16* __restrict__ wblo)
{
    const size_t idx = ((size_t)blockIdx.x * 256 + threadIdx.x) * 8;
    const float4 a = *(const float4*)(&W[idx]);
    const float4 b = *(const float4*)(&W[idx + 4]);
    float v[8] = {a.x, a.y, a.z, a.w, b.x, b.y, b.z, b.w};
    u16 H[8], L[8];
#pragma unroll
    for (int j = 0; j < 8; ++j) {
        H[j] = f2bf(v[j]);
        L[j] = f2bf(v[j] - bf2f(H[j]));
    }
    *(bf16x8*)&wbhi[idx] = *(bf16x8*)H;
    *(bf16x8*)&wblo[idx] = *(bf16x8*)L;
}

// ---------------------------------------------------------------------------
// Kernel 1: QKV projection, split-bf16 MFMA GEMM + T14 register prefetch.
// (validated round-9 structure; staging moved through registers, write-late)
// ---------------------------------------------------------------------------
__global__ __launch_bounds__(256, 2)
void qkv_mfma(const u16* __restrict__ fthi, const u16* __restrict__ ftlo,
              const u16* __restrict__ wbhi, const u16* __restrict__ wblo,
              const float* __restrict__ EH, const float* __restrict__ EW,
              u16* __restrict__ qhi, u16* __restrict__ qlo,
              u16* __restrict__ khi, u16* __restrict__ klo,
              u16* __restrict__ vtg)
{
    __shared__ u16 smem[16384];            // 32 KB
    u16* Ah = smem;                        // [64][64] swizzled (token x k)
    u16* Al = smem + 4096;
    u16* Bh = smem + 8192;                 // [64][64] swizzled (o x k)
    u16* Bl = smem + 12288;
    float* Od = (float*)smem;              // epilogue reuse [64][68] f32

    const int tid  = threadIdx.x;
    const int lane = tid & 63;
    const int wave = tid >> 6;
    const int l15  = lane & 15;
    const int lg   = lane >> 4;
    const int wm   = wave >> 1;
    const int wn   = wave & 1;

    const int ii = blockIdx.x * 64;
    const int oo = blockIdx.y * 64;
    const int b  = blockIdx.z;
    const size_t fbase = (size_t)b * NTOK * DIM;

    // staging geometry: u=0,1 -> row jrow+32u, col chunk dc
    const int jrow = tid >> 3;
    const int dc   = (tid & 7) * 8;
    const int ld0  = jrow * 64 + (dc ^ ((jrow & 7) << 3));   // +2048 per u
    const size_t ga0 = fbase + (size_t)(ii + jrow) * DIM + dc;  // +32*DIM per u
    const size_t gb0 = (size_t)(oo + jrow) * DIM + dc;

    f32x4 acc[2][2];
#pragma unroll
    for (int mf = 0; mf < 2; ++mf)
#pragma unroll
        for (int nf = 0; nf < 2; ++nf) { acc[mf][nf][0] = 0.f; acc[mf][nf][1] = 0.f; acc[mf][nf][2] = 0.f; acc[mf][nf][3] = 0.f; }

    bf16x8 pah[2], pal[2], pbh[2], pbl[2];
    // prologue: load kt=0 and stage
#pragma unroll
    for (int u = 0; u < 2; ++u) {
        pah[u] = *(const bf16x8*)(fthi + ga0 + (size_t)u * 32 * DIM);
        pal[u] = *(const bf16x8*)(ftlo + ga0 + (size_t)u * 32 * DIM);
        pbh[u] = *(const bf16x8*)(wbhi + gb0 + (size_t)u * 32 * DIM);
        pbl[u] = *(const bf16x8*)(wblo + gb0 + (size_t)u * 32 * DIM);
    }
#pragma unroll
    for (int u = 0; u < 2; ++u) {
        *(bf16x8*)&Ah[ld0 + 2048 * u] = pah[u];
        *(bf16x8*)&Al[ld0 + 2048 * u] = pal[u];
        *(bf16x8*)&Bh[ld0 + 2048 * u] = pbh[u];
        *(bf16x8*)&Bl[ld0 + 2048 * u] = pbl[u];
    }
    __syncthreads();

    for (int kt = 0; kt < DIM; kt += 64) {
        if (kt < DIM - 64) {
            // issue next K-tile loads early (latency hides under MFMA)
#pragma unroll
            for (int u = 0; u < 2; ++u) {
                pah[u] = *(const bf16x8*)(fthi + ga0 + kt + 64 + (size_t)u * 32 * DIM);
                pal[u] = *(const bf16x8*)(ftlo + ga0 + kt + 64 + (size_t)u * 32 * DIM);
                pbh[u] = *(const bf16x8*)(wbhi + gb0 + kt + 64 + (size_t)u * 32 * DIM);
                pbl[u] = *(const bf16x8*)(wblo + gb0 + kt + 64 + (size_t)u * 32 * DIM);
            }
        }

#pragma unroll
        for (int kc = 0; kc < 2; ++kc) {
            const int ko = kc * 32 + lg * 8;
            bf16x8 af_h[2], af_l[2], bf_h[2], bf_l[2];
#pragma unroll
            for (int mf = 0; mf < 2; ++mf) {
                const int ar = wm * 32 + mf * 16 + l15;
                const int off = ar * 64 + (ko ^ ((ar & 7) << 3));
                af_h[mf] = *(const bf16x8*)&Ah[off];
                af_l[mf] = *(const bf16x8*)&Al[off];
            }
#pragma unroll
            for (int nf = 0; nf < 2; ++nf) {
                const int br = wn * 32 + nf * 16 + l15;
                const int off = br * 64 + (ko ^ ((br & 7) << 3));
                bf_h[nf] = *(const bf16x8*)&Bh[off];
                bf_l[nf] = *(const bf16x8*)&Bl[off];
            }
#pragma unroll
            for (int mf = 0; mf < 2; ++mf)
#pragma unroll
                for (int nf = 0; nf < 2; ++nf) {
                    acc[mf][nf] = __builtin_amdgcn_mfma_f32_16x16x32_bf16(af_h[mf], bf_h[nf], acc[mf][nf], 0, 0, 0);
                    acc[mf][nf] = __builtin_amdgcn_mfma_f32_16x16x32_bf16(af_h[mf], bf_l[nf], acc[mf][nf], 0, 0, 0);
                    acc[mf][nf] = __builtin_amdgcn_mfma_f32_16x16x32_bf16(af_l[mf], bf_h[nf], acc[mf][nf], 0, 0, 0);
                }
        }
        __syncthreads();                   // all waves done reading this K-tile
        if (kt < DIM - 64) {
#pragma unroll
            for (int u = 0; u < 2; ++u) {
                *(bf16x8*)&Ah[ld0 + 2048 * u] = pah[u];
                *(bf16x8*)&Al[ld0 + 2048 * u] = pal[u];
                *(bf16x8*)&Bh[ld0 + 2048 * u] = pbh[u];
                *(bf16x8*)&Bl[ld0 + 2048 * u] = pbl[u];
            }
        }
        __syncthreads();                   // next tile visible
    }

    // D layout (validated): col = l15, row = lg*4 + r
#pragma unroll
    for (int mf = 0; mf < 2; ++mf)
#pragma unroll
        for (int nf = 0; nf < 2; ++nf)
#pragma unroll
            for (int r = 0; r < 4; ++r)
                Od[(wm * 32 + mf * 16 + lg * 4 + r) * 68 + wn * 32 + nf * 16 + l15] = acc[mf][nf][r];
    __syncthreads();

    const int s  = oo >> 9;
    const int h  = (oo >> 7) & 3;
    const int d0 = oo & 127;
    const int bh = b * HEADS + h;
    const float scale = 0.08838834764831845f;   // 128^-0.5

    if (s == 2) {
#pragma unroll
        for (int u = 0; u < 2; ++u) {
            const int idx = tid + 256 * u;
            const int dr = idx >> 3;
            const int tc = (idx & 7) * 8;
            u16 P[8];
#pragma unroll
            for (int j = 0; j < 8; ++j)
                P[j] = f2bf(Od[(tc + j) * 68 + dr]);
            *(bf16x8*)&vtg[((size_t)bh * DHEAD + d0 + dr) * NTOK + ii + tc] = *(bf16x8*)P;
        }
    } else {
        u16* hi = s ? khi : qhi;
        u16* lo = s ? klo : qlo;
#pragma unroll
        for (int u = 0; u < 2; ++u) {
            const int idx = tid + 256 * u;
            const int tr = idx >> 3;
            const int dcc = (idx & 7) * 8;
            const int i  = ii + tr;
            float v[8];
            const float4 p0 = *(const float4*)&Od[tr * 68 + dcc];
            const float4 p1 = *(const float4*)&Od[tr * 68 + dcc + 4];
            v[0] = p0.x; v[1] = p0.y; v[2] = p0.z; v[3] = p0.w;
            v[4] = p1.x; v[5] = p1.y; v[6] = p1.z; v[7] = p1.w;
            if (s == 0) {
#pragma unroll
                for (int j = 0; j < 8; ++j) v[j] *= scale;
            } else {
                const float* eh = &EH[(i >> 5) * DHEAD + d0 + dcc];
                const float* ew = &EW[(i & 31) * DHEAD + d0 + dcc];
                const float4 e0 = *(const float4*)eh, e1 = *(const float4*)(eh + 4);
                const float4 w0 = *(const float4*)ew, w1 = *(const float4*)(ew + 4);
                v[0] += e0.x + w0.x; v[1] += e0.y + w0.y; v[2] += e0.z + w0.z; v[3] += e0.w + w0.w;
                v[4] += e1.x + w1.x; v[5] += e1.y + w1.y; v[6] += e1.z + w1.z; v[7] += e1.w + w1.w;
            }
            u16 H[8], L[8];
#pragma unroll
            for (int j = 0; j < 8; ++j) {
                H[j] = f2bf(v[j]);
                L[j] = f2bf(v[j] - bf2f(H[j]));
            }
            const size_t o = ((size_t)bh * NTOK + i) * DHEAD + d0 + dcc;
            *(bf16x8*)&hi[o] = *(bf16x8*)H;
            *(bf16x8*)&lo[o] = *(bf16x8*)L;
        }
    }
}

// ---------------------------------------------------------------------------
// Kernel 2: MFMA flash attention + T14 register prefetch + T5 setprio.
// (round-8-validated layouts/swizzles unchanged; staging write-late)
// ---------------------------------------------------------------------------
#define QB 64
#define KB 64

__global__ __launch_bounds__(256, 2)
void attn_mfma(const u16* __restrict__ qh, const u16* __restrict__ ql,
               const u16* __restrict__ kh, const u16* __restrict__ kl,
               const u16* __restrict__ vtg, float* __restrict__ out)
{
    __shared__ u16 smem[28672];            // 57344 B -> 2 blocks/CU
    u16* Kh = smem;                        // [64][128] swizzled
    u16* Kl = smem + 8192;
    u16* Vt = smem + 16384;                // [128][64] swizzled
    u16* Pl = smem + 24576;                // 4 waves x [16][64] swizzled
    float* Od = (float*)smem;              // epilogue reuse [128][72]

    const int tid  = threadIdx.x;
    const int lane = tid & 63;
    const int wave = tid >> 6;
    const int l15  = lane & 15;
    const int lg   = lane >> 4;

    const int ii = blockIdx.x * QB;
    const int bh = blockIdx.y;
    const size_t base = (size_t)bh * NTOK * DHEAD;   // also vt base

    // staging geometry: K u=0..3 -> row kj+16u; V u=0..3 -> row vd+32u
    const int kj  = tid >> 4;
    const int kdc = (tid & 15) * 8;
    const int vd  = tid >> 3;
    const int vjc = (tid & 7) * 8;
    const int ldk0 = kj * DHEAD + (kdc ^ ((kj & 7) << 3));   // +2048 per u
    const int ldv0 = vd * KB   + (vjc ^ ((vd & 7) << 3));    // +2048 per u
    const size_t gk0 = base + (size_t)kj * DHEAD + kdc;      // + jt*8192 + 2048u
    const size_t gv0 = base + (size_t)vd * NTOK + vjc;       // + jt*64 + 32768u

    bf16x8 qfh[4], qfl[4];
    {
        const size_t qoff = base + (size_t)(ii + wave * 16 + l15) * DHEAD + lg * 8;
#pragma unroll
        for (int kc = 0; kc < 4; ++kc) {
            qfh[kc] = *(const bf16x8*)(qh + qoff + kc * 32);
            qfl[kc] = *(const bf16x8*)(ql + qoff + kc * 32);
        }
    }

    f32x4 o[8];
#pragma unroll
    for (int n = 0; n < 8; ++n) { o[n][0] = 0.f; o[n][1] = 0.f; o[n][2] = 0.f; o[n][3] = 0.f; }
    float mrow[4], lrow[4];
#pragma unroll
    for (int r = 0; r < 4; ++r) { mrow[r] = -3.0e38f; lrow[r] = 0.f; }

    bf16x8 pkh[4], pkl[4], pv[4];
    // prologue: load + stage jt=0
#pragma unroll
    for (int u = 0; u < 4; ++u) {
        pkh[u] = *(const bf16x8*)(kh  + gk0 + 2048 * u);
        pkl[u] = *(const bf16x8*)(kl  + gk0 + 2048 * u);
        pv[u]  = *(const bf16x8*)(vtg + gv0 + 32768 * (size_t)u);
    }
#pragma unroll
    for (int u = 0; u < 4; ++u) {
        *(bf16x8*)&Kh[ldk0 + 2048 * u] = pkh[u];
        *(bf16x8*)&Kl[ldk0 + 2048 * u] = pkl[u];
        *(bf16x8*)&Vt[ldv0 + 2048 * u] = pv[u];
    }
    __syncthreads();

    for (int jt = 0; jt < NTOK / KB; ++jt) {
        if (jt < NTOK / KB - 1) {
            // issue next-tile loads; latency hides under QKT+softmax+PV
            const size_t gk = gk0 + (size_t)(jt + 1) * 8192;
            const size_t gv = gv0 + (size_t)(jt + 1) * 64;
#pragma unroll
            for (int u = 0; u < 4; ++u) {
                pkh[u] = *(const bf16x8*)(kh  + gk + 2048 * u);
                pkl[u] = *(const bf16x8*)(kl  + gk + 2048 * u);
                pv[u]  = *(const bf16x8*)(vtg + gv + 32768 * (size_t)u);
            }
        }

        // S = Q K'^T  (split bf16)
        f32x4 s[4];
        __builtin_amdgcn_s_setprio(1);
#pragma unroll
        for (int n = 0; n < 4; ++n) {
            f32x4 acc = {0.f, 0.f, 0.f, 0.f};
            const int j  = n * 16 + l15;
            const int ro = j * DHEAD;
            const int sw = (j & 7) << 3;
#pragma unroll
            for (int kc = 0; kc < 4; ++kc) {
                const int off = ro + ((kc * 32 + lg * 8) ^ sw);
                const bf16x8 kb = *(const bf16x8*)&Kh[off];
                const bf16x8 lb = *(const bf16x8*)&Kl[off];
                acc = __builtin_amdgcn_mfma_f32_16x16x32_bf16(qfh[kc], kb, acc, 0, 0, 0);
                acc = __builtin_amdgcn_mfma_f32_16x16x32_bf16(qfh[kc], lb, acc, 0, 0, 0);
                acc = __builtin_amdgcn_mfma_f32_16x16x32_bf16(qfl[kc], kb, acc, 0, 0, 0);
            }
            s[n] = acc;
        }
        __builtin_amdgcn_s_setprio(0);

        // online softmax
        float tmax[4];
#pragma unroll
        for (int r = 0; r < 4; ++r)
            tmax[r] = fmaxf(fmaxf(s[0][r], s[1][r]), fmaxf(s[2][r], s[3][r]));
#pragma unroll
        for (int off = 1; off < 16; off <<= 1)
#pragma unroll
            for (int r = 0; r < 4; ++r)
                tmax[r] = fmaxf(tmax[r], __shfl_xor(tmax[r], off));

        float fr[4], psum[4];
#pragma unroll
        for (int r = 0; r < 4; ++r) {
            const float mn = fmaxf(mrow[r], tmax[r]);
            fr[r] = __expf(mrow[r] - mn);
            mrow[r] = mn;
            psum[r] = 0.f;
        }
        const int pbase = wave * 1024;
#pragma unroll
        for (int n = 0; n < 4; ++n)
#pragma unroll
            for (int r = 0; r < 4; ++r) {
                const float p = __expf(s[n][r] - mrow[r]);
                psum[r] += p;
                const int row = lg * 4 + r;
                Pl[pbase + row * KB + ((n * 16 + l15) ^ ((row & 7) << 3))] = f2bf(p);
            }
#pragma unroll
        for (int off = 1; off < 16; off <<= 1)
#pragma unroll
            for (int r = 0; r < 4; ++r)
                psum[r] += __shfl_xor(psum[r], off);
#pragma unroll
        for (int r = 0; r < 4; ++r) lrow[r] = lrow[r] * fr[r] + psum[r];
#pragma unroll
        for (int n = 0; n < 8; ++n)
#pragma unroll
            for (int r = 0; r < 4; ++r) o[n][r] *= fr[r];

        // PV
        const bf16x8 pf0 = *(const bf16x8*)&Pl[pbase + l15 * KB + ((lg * 8) ^ ((l15 & 7) << 3))];
        const bf16x8 pf1 = *(const bf16x8*)&Pl[pbase + l15 * KB + ((32 + lg * 8) ^ ((l15 & 7) << 3))];
        __builtin_amdgcn_s_setprio(1);
#pragma unroll
        for (int nd = 0; nd < 8; ++nd) {
            const int d  = nd * 16 + l15;
            const int vo = d * KB;
            const int sw = (d & 7) << 3;
            o[nd] = __builtin_amdgcn_mfma_f32_16x16x32_bf16(
                        pf0, *(const bf16x8*)&Vt[vo + ((lg * 8) ^ sw)], o[nd], 0, 0, 0);
            o[nd] = __builtin_amdgcn_mfma_f32_16x16x32_bf16(
                        pf1, *(const bf16x8*)&Vt[vo + ((32 + lg * 8) ^ sw)], o[nd], 0, 0, 0);
        }
        __builtin_amdgcn_s_setprio(0);

        __syncthreads();                   // all waves done reading K/V/P LDS
        if (jt < NTOK / KB - 1) {
#pragma unroll
            for (int u = 0; u < 4; ++u) {
                *(bf16x8*)&Kh[ldk0 + 2048 * u] = pkh[u];
                *(bf16x8*)&Kl[ldk0 + 2048 * u] = pkl[u];
                *(bf16x8*)&Vt[ldv0 + 2048 * u] = pv[u];
            }
        }
        __syncthreads();                   // next tile visible
    }

    // epilogue: normalize, transpose via LDS, coalesced store out[b][h*128+d][i]
    __syncthreads();
    float invl[4];
#pragma unroll
    for (int r = 0; r < 4; ++r) invl[r] = 1.0f / lrow[r];
#pragma unroll
    for (int nd = 0; nd < 8; ++nd)
#pragma unroll
        for (int r = 0; r < 4; ++r)
            Od[(nd * 16 + l15) * 72 + wave * 16 + lg * 4 + r] = o[nd][r] * invl[r];
    __syncthreads();

    const int b = bh >> 2, h = bh & 3;
    float* dst = out + ((size_t)b * 512 + h * DHEAD) * NTOK + ii;
#pragma unroll
    for (int u = 0; u < 4; ++u) {
        const int idx = tid + 256 * u;
        const int d  = idx >> 3;
        const int jc = (idx & 7) * 8;
        *(float4*)(dst + (size_t)d * NTOK + jc)     = *(const float4*)&Od[d * 72 + jc];
        *(float4*)(dst + (size_t)d * NTOK + jc + 4) = *(const float4*)&Od[d * 72 + jc + 4];
    }
}

// ---------------------------------------------------------------------------
extern "C" void kernel_launch(void* const* d_in, const int* in_sizes, int n_in,
                              void* d_out, int out_size, void* d_ws, size_t ws_size,
                              hipStream_t stream)
{
    (void)in_sizes; (void)n_in; (void)out_size; (void)ws_size;
    const float* fmap  = (const float*)d_in[0];
    const float* w_qkv = (const float*)d_in[1];
    const float* eh    = (const float*)d_in[2];
    const float* ew    = (const float*)d_in[3];
    float* out = (float*)d_out;

    const size_t per = (size_t)BATCH * HEADS * NTOK * DHEAD;   // 8.39M elems
    u16* qhi  = (u16*)d_ws;
    u16* qlo  = qhi + per;
    u16* khi  = qlo + per;
    u16* klo  = khi + per;
    u16* vtg  = klo + per;
    u16* fthi = vtg + per;
    u16* ftlo = fthi + per;
    u16* wbhi = ftlo + per;
    u16* wblo = wbhi + (size_t)OCH * DIM;   // total ~120.6 MB

    hipLaunchKernelGGL(prep_ft, dim3(NTOK / 32, DIM / 32, BATCH), dim3(256), 0, stream,
                       fmap, fthi, ftlo);
    hipLaunchKernelGGL(prep_w, dim3((OCH * DIM) / (256 * 8)), dim3(256), 0, stream,
                       w_qkv, wbhi, wblo);
    hipLaunchKernelGGL(qkv_mfma, dim3(NTOK / 64, OCH / 64, BATCH), dim3(256), 0, stream,
                       fthi, ftlo, wbhi, wblo, eh, ew, qhi, qlo, khi, klo, vtg);
    hipLaunchKernelGGL(attn_mfma, dim3(NTOK / QB, BATCH * HEADS), dim3(256), 0, stream,
                       qhi, qlo, khi, klo, vtg, out);
}